// Round 5
// baseline (194.144 us; speedup 1.0000x reference)
//
#include <hip/hip_runtime.h>

// AttentionHead: B=4, S=2048, D=1024, fp32 in/out, bf16 MFMA compute.
// Algebraic restructure: G = Wq·Wk^T  =>  S = Xq·G·Xk^T (K-projection eliminated).
// Max-free softmax: P = exp(S) fused into scores epilogue + row-sum partials;
// PV scales by 1/rowsum. All GEMM grids single-round (<=1280 blocks).

typedef __attribute__((ext_vector_type(8))) short short8;
typedef __attribute__((ext_vector_type(4))) float floatx4;

static constexpr long long XE = 8388608LL;  // 4*2048*1024
static constexpr long long WE = 1048576LL;  // 1024*1024

static __device__ __forceinline__ unsigned short f2b(float f) {
  unsigned u = __builtin_bit_cast(unsigned, f);
  u = (u + 0x7fffu + ((u >> 16) & 1u)) >> 16;
  return (unsigned short)u;
}

static __device__ __forceinline__ void gload16(const unsigned short* g, unsigned short* l) {
  __builtin_amdgcn_global_load_lds(
      (const __attribute__((address_space(1))) unsigned int*)g,
      (__attribute__((address_space(3))) unsigned int*)l, 16, 0, 0);
}

// 128x128 tile, BK=64, 4 waves (2x2), 4x4 16x16x32 bf16 frags. Proven core.
// LDS row = 8 chunks of 16B; chunk c of row r holds global chunk c^(r&7).
static __device__ __forceinline__ void gemm_loop(
    const unsigned short* __restrict__ A, const unsigned short* __restrict__ Bt,
    int lda, int ldb, int nk, int bi, int bj,
    unsigned short* lA, unsigned short* lB, floatx4 acc[4][4]) {
  const int t = threadIdx.x, wave = t >> 6, lane = t & 63;
  const int wr = wave >> 1, wc = wave & 1;
  const int sr = lane >> 3;
  const int sc = ((lane & 7) ^ sr) * 8;
  const unsigned short* gA = A + (long long)(bi * 128 + wave * 32 + sr) * lda + sc;
  const unsigned short* gB = Bt + (long long)(bj * 128 + wave * 32 + sr) * ldb + sc;
  unsigned short* lAw = lA + wave * 2048;
  unsigned short* lBw = lB + wave * 2048;
  const int frow = lane & 15, hi = lane >> 4;

  for (int ks = 0; ks < nk; ++ks) {
    const long long k0 = (long long)ks * 64;
    __syncthreads();
#pragma unroll
    for (int g = 0; g < 4; ++g) {
      gload16(gA + (long long)g * 8 * lda + k0, lAw + g * 512);
      gload16(gB + (long long)g * 8 * ldb + k0, lBw + g * 512);
    }
    __syncthreads();
#pragma unroll
    for (int kk = 0; kk < 2; ++kk) {
      const int ch = (kk * 4 + hi) ^ (frow & 7);
      short8 af[4], bf[4];
#pragma unroll
      for (int m = 0; m < 4; ++m)
        af[m] = *(const short8*)&lA[(wr * 64 + m * 16 + frow) * 64 + ch * 8];
#pragma unroll
      for (int n = 0; n < 4; ++n)
        bf[n] = *(const short8*)&lB[(wc * 64 + n * 16 + frow) * 64 + ch * 8];
#pragma unroll
      for (int m = 0; m < 4; ++m)
#pragma unroll
        for (int n = 0; n < 4; ++n)
          acc[m][n] = __builtin_amdgcn_mfma_f32_16x16x32_bf16(af[m], bf[n], acc[m][n], 0, 0, 0);
    }
  }
}

// Gt[j][i] = sum_d Wk[j][d]*Wq[i][d]  (both untransposed bf16), grid (8,8)
__global__ __launch_bounds__(256) void gt_kernel(
    const unsigned short* __restrict__ WkB, const unsigned short* __restrict__ WqB,
    unsigned short* __restrict__ Gt) {
  __shared__ __align__(16) unsigned short lA[8192], lB[8192];
  floatx4 acc[4][4] = {};
  gemm_loop(WkB, WqB, 1024, 1024, 16, blockIdx.x, blockIdx.y, lA, lB, acc);
  const int tid = threadIdx.x, wave = tid >> 6, lane = tid & 63;
  const int wr = wave >> 1, wc = wave & 1, frow = lane & 15, hi = lane >> 4;
  const long long crow0 = (long long)blockIdx.x * 128 + wr * 64 + hi * 4;
  const int ccol = blockIdx.y * 128 + wc * 64 + frow;
#pragma unroll
  for (int m = 0; m < 4; ++m)
#pragma unroll
    for (int j = 0; j < 4; ++j) {
      unsigned short* cp = Gt + (crow0 + m * 16 + j) * 1024 + ccol;
#pragma unroll
      for (int n = 0; n < 4; ++n) cp[n * 16] = f2b(acc[m][n][j]);
    }
}

// z=0: T = Xq @ Gt^T-form -> Tb [8192][1024] ; z=1: V^T = Wv^T @ Xv^T -> Vt [1024][8192]
__global__ __launch_bounds__(256) void projTV(
    const unsigned short* __restrict__ Xb, const unsigned short* __restrict__ WvT,
    const unsigned short* __restrict__ Gt, unsigned short* __restrict__ Tb,
    unsigned short* __restrict__ Vt) {
  __shared__ __align__(16) unsigned short lA[8192], lB[8192];
  const int z = blockIdx.z;
  const unsigned short *A, *B;
  unsigned short* C;
  int ldc, bi, bj;
  if (z == 0) { A = Xb + XE; B = Gt; C = Tb; ldc = 1024; bi = blockIdx.x; bj = blockIdx.y; }
  else        { A = WvT;     B = Xb; C = Vt; ldc = 8192; bi = blockIdx.y; bj = blockIdx.x; }
  floatx4 acc[4][4] = {};
  gemm_loop(A, B, 1024, 1024, 16, bi, bj, lA, lB, acc);
  const int tid = threadIdx.x, wave = tid >> 6, lane = tid & 63;
  const int wr = wave >> 1, wc = wave & 1, frow = lane & 15, hi = lane >> 4;
  const long long crow0 = (long long)bi * 128 + wr * 64 + hi * 4;
  const int ccol = bj * 128 + wc * 64 + frow;
#pragma unroll
  for (int m = 0; m < 4; ++m)
#pragma unroll
    for (int j = 0; j < 4; ++j) {
      unsigned short* cp = C + (crow0 + m * 16 + j) * (long long)ldc + ccol;
#pragma unroll
      for (int n = 0; n < 4; ++n) cp[n * 16] = f2b(acc[m][n][j]);
    }
}

// tri grid (136,4): S-tile = T·Xk^T ; P = exp(S/32) bf16 (causal-masked) ;
// per-tile row-sum partials -> Rpart[b][bj][2048] (plain stores, deterministic).
__global__ __launch_bounds__(256) void scores_exp(
    const unsigned short* __restrict__ Tb, const unsigned short* __restrict__ Xk,
    unsigned short* __restrict__ P, float* __restrict__ Rpart) {
  __shared__ __align__(16) unsigned short lA[8192], lB[8192];
  int t = blockIdx.x, bi = 0;
  while ((bi + 1) * (bi + 2) / 2 <= t) ++bi;
  const int bj = t - bi * (bi + 1) / 2;
  const long long b = blockIdx.y;
  floatx4 acc[4][4] = {};
  gemm_loop(Tb + b * 2048 * 1024, Xk + b * 2048 * 1024, 1024, 1024, 16, bi, bj, lA, lB, acc);

  const int tid = threadIdx.x, wave = tid >> 6, lane = tid & 63;
  const int wr = wave >> 1, wc = wave & 1, frow = lane & 15, hi = lane >> 4;
  const bool diag = (bi == bj);
  float rp[4][4];
#pragma unroll
  for (int m = 0; m < 4; ++m)
#pragma unroll
    for (int j = 0; j < 4; ++j) {
      const int r = wr * 64 + hi * 4 + m * 16 + j;
      float s = 0.f;
#pragma unroll
      for (int n = 0; n < 4; ++n) {
        const int c = wc * 64 + frow + n * 16;
        float e = __expf(acc[m][n][j] * 0.03125f);
        if (diag && c > r) e = 0.f;
        acc[m][n][j] = e;
        s += e;
      }
      rp[m][j] = s;
    }
  // reduce row partials over the 16 frow lanes (stays within 16-lane group)
#pragma unroll
  for (int m = 0; m < 4; ++m)
#pragma unroll
    for (int j = 0; j < 4; ++j) {
      rp[m][j] += __shfl_xor(rp[m][j], 1);
      rp[m][j] += __shfl_xor(rp[m][j], 2);
      rp[m][j] += __shfl_xor(rp[m][j], 4);
      rp[m][j] += __shfl_xor(rp[m][j], 8);
    }
  // P write
  unsigned short* C = P + b * 2048 * 2048;
  const long long crow0 = (long long)bi * 128 + wr * 64 + hi * 4;
  const int ccol = bj * 128 + wc * 64 + frow;
#pragma unroll
  for (int m = 0; m < 4; ++m)
#pragma unroll
    for (int j = 0; j < 4; ++j) {
      unsigned short* cp = C + (crow0 + m * 16 + j) * 2048LL + ccol;
#pragma unroll
      for (int n = 0; n < 4; ++n) cp[n * 16] = f2b(acc[m][n][j]);
    }
  // cross-wave (wc) combine via LDS, then one partial per row
  __syncthreads();
  float* red = (float*)lA;
  if (frow == 0) {
#pragma unroll
    for (int m = 0; m < 4; ++m)
#pragma unroll
      for (int j = 0; j < 4; ++j)
        red[(wr * 64 + hi * 4 + m * 16 + j) * 2 + wc] = rp[m][j];
  }
  __syncthreads();
  if (tid < 128)
    Rpart[(b * 16 + bj) * 2048 + bi * 128 + tid] = red[tid * 2] + red[tid * 2 + 1];
}

// Rinv[b][row] = 1 / sum_{bj<=row>>7} Rpart[b][bj][row]
__global__ __launch_bounds__(256) void rowsum(
    const float* __restrict__ Rpart, float* __restrict__ Rinv) {
  const int t = blockIdx.x * 256 + threadIdx.x;  // 0..8191
  const int b = t >> 11, row = t & 2047;
  const int nb = (row >> 7) + 1;
  float s = 0.f;
  for (int bj = 0; bj < nb; ++bj) s += Rpart[(b * 16 + bj) * 2048 + row];
  Rinv[t] = 1.f / s;
}

// O = (P V) * Rinv ; 1D grid 512, heavy+light pairing: blocks c and c+256 sum const.
__global__ __launch_bounds__(256) void pv_kernel(
    const unsigned short* __restrict__ P, const unsigned short* __restrict__ Vt,
    const float* __restrict__ Rinv, float* __restrict__ out) {
  __shared__ __align__(16) unsigned short lA[8192], lB[8192];
  const int c = blockIdx.x;
  const int t = (c < 256) ? c : 767 - c;
  const int bi = 15 - (t >> 5);
  const int sub = t & 31;
  const int b = sub >> 3, bj = sub & 7;
  floatx4 acc[4][4] = {};
  gemm_loop(P + (long long)b * 2048 * 2048, Vt + (long long)b * 2048, 2048, 8192,
            (bi + 1) * 2, bi, bj, lA, lB, acc);
  const int tid = threadIdx.x, wave = tid >> 6, lane = tid & 63;
  const int wr = wave >> 1, wc = wave & 1, frow = lane & 15, hi = lane >> 4;
  float* C = out + (long long)b * 2048 * 1024;
  const float* Ri = Rinv + b * 2048;
#pragma unroll
  for (int m = 0; m < 4; ++m)
#pragma unroll
    for (int j = 0; j < 4; ++j) {
      const int row = bi * 128 + wr * 64 + hi * 4 + m * 16 + j;
      const float riv = Ri[row];
      float* cp = C + (long long)row * 1024 + bj * 128 + wc * 64 + frow;
#pragma unroll
      for (int n = 0; n < 4; ++n) cp[n * 16] = acc[m][n][j] * riv;
    }
}

// fp32->bf16 converts: X's (grid 1024,3): y0 Xv, y1 Xq, y2 Xk
__global__ __launch_bounds__(256) void cvtX(
    const float* __restrict__ Xk, const float* __restrict__ Xv,
    const float* __restrict__ Xq, unsigned short* __restrict__ Xb) {
  const float* in = blockIdx.y == 0 ? Xv : (blockIdx.y == 1 ? Xq : Xk);
  unsigned short* o = Xb + (long long)blockIdx.y * XE;
  const int n4 = (int)(XE / 4);
  const int stride = 1024 * 256;
  for (int i = blockIdx.x * 256 + threadIdx.x; i < n4; i += stride) {
    float4 x = ((const float4*)in)[i];
    ushort4 v;
    v.x = f2b(x.x); v.y = f2b(x.y); v.z = f2b(x.z); v.w = f2b(x.w);
    ((ushort4*)o)[i] = v;
  }
}

// Wq, Wk plain converts (grid 128,2): y0 Wq, y1 Wk
__global__ __launch_bounds__(256) void cvtW(
    const float* __restrict__ Wq, const float* __restrict__ Wk,
    unsigned short* __restrict__ WqB, unsigned short* __restrict__ WkB) {
  const float* in = blockIdx.y == 0 ? Wq : Wk;
  unsigned short* o = blockIdx.y == 0 ? WqB : WkB;
  const int n4 = (int)(WE / 4);
  const int stride = 128 * 256;
  for (int i = blockIdx.x * 256 + threadIdx.x; i < n4; i += stride) {
    float4 x = ((const float4*)in)[i];
    ushort4 v;
    v.x = f2b(x.x); v.y = f2b(x.y); v.z = f2b(x.z); v.w = f2b(x.w);
    ((ushort4*)o)[i] = v;
  }
}

// Wv [i][o] fp32 -> WvT bf16 [o][i], grid (16,16)
__global__ __launch_bounds__(256) void wcvtV(
    const float* __restrict__ Wv, unsigned short* __restrict__ WvT) {
  __shared__ unsigned short tile[64][65];
  const int t = threadIdx.x;
  const int i0 = blockIdx.x * 64, j0 = blockIdx.y * 64;
#pragma unroll
  for (int r = 0; r < 16; ++r) {
    int lin = r * 256 + t;
    int i = lin >> 6, j = lin & 63;
    tile[i][j] = f2b(Wv[(long long)(i0 + i) * 1024 + j0 + j]);
  }
  __syncthreads();
#pragma unroll
  for (int r = 0; r < 16; ++r) {
    int lin = r * 256 + t;
    int o = lin >> 6, i = lin & 63;
    WvT[(long long)(j0 + o) * 1024 + i0 + i] = tile[i][o];
  }
}

extern "C" void kernel_launch(void* const* d_in, const int* in_sizes, int n_in,
                              void* d_out, int out_size, void* d_ws, size_t ws_size,
                              hipStream_t stream) {
  const float* Xk = (const float*)d_in[0];
  const float* Xv = (const float*)d_in[1];
  const float* Xq = (const float*)d_in[2];
  const float* Wk = (const float*)d_in[3];
  const float* Wv = (const float*)d_in[4];
  const float* Wq = (const float*)d_in[5];
  float* out = (float*)d_out;

  // ws (ushort elems): Xb[3XE: Xv|Xq|Xk] WqB[WE] WkB[WE] WvT[WE] Gt[WE]
  //                    Tb[XE] Vt[XE] Rpart[262144] Rinv[16384]  = 92.8 MB
  // Pbuf (bf16 P, 4*2048*2048 = 2XE) aliases Xv|Xq (dead after projTV).
  unsigned short* ws = (unsigned short*)d_ws;
  unsigned short* Xb = ws;
  unsigned short* WqB = ws + 3 * XE;
  unsigned short* WkB = WqB + WE;
  unsigned short* WvT = WkB + WE;
  unsigned short* Gt = WvT + WE;
  unsigned short* Tb = Gt + WE;
  unsigned short* Vt = Tb + XE;
  float* Rpart = (float*)(Vt + XE);
  float* Rinv = Rpart + 131072;
  unsigned short* Pbuf = ws;  // alias

  cvtX<<<dim3(1024, 3), 256, 0, stream>>>(Xk, Xv, Xq, Xb);
  cvtW<<<dim3(128, 2), 256, 0, stream>>>(Wq, Wk, WqB, WkB);
  wcvtV<<<dim3(16, 16), 256, 0, stream>>>(Wv, WvT);
  gt_kernel<<<dim3(8, 8), 256, 0, stream>>>(WkB, WqB, Gt);
  projTV<<<dim3(64, 8, 2), 256, 0, stream>>>(Xb, WvT, Gt, Tb, Vt);
  scores_exp<<<dim3(136, 4), 256, 0, stream>>>(Tb, Xb + 2 * XE, Pbuf, Rpart);
  rowsum<<<32, 256, 0, stream>>>(Rpart, Rinv);
  pv_kernel<<<512, 256, 0, stream>>>(Pbuf, Vt, Rinv, out);
}

// Round 6
// 188.686 us; speedup vs baseline: 1.0289x; 1.0289x over previous
//
#include <hip/hip_runtime.h>

// AttentionHead: B=4, S=2048, D=1024, fp32 in/out, bf16 MFMA compute.
// G = Wq·Wk^T  =>  S = Xq·G·Xk^T (K-projection eliminated).
// Max-free softmax: P = exp(S/32) fused into scores epilogue + row-sum partials;
// PV scales by 1/rowsum.
// GEMM core: 128x128 tile, BK=64, double-buffered LDS (64 KB), 2-phase
// pipeline with counted end-of-iter vmcnt(0) (T3-minimum recipe).

typedef __attribute__((ext_vector_type(8))) short short8;
typedef __attribute__((ext_vector_type(4))) float floatx4;

static constexpr long long XE = 8388608LL;  // 4*2048*1024
static constexpr long long WE = 1048576LL;  // 1024*1024

static __device__ __forceinline__ unsigned short f2b(float f) {
  unsigned u = __builtin_bit_cast(unsigned, f);
  u = (u + 0x7fffu + ((u >> 16) & 1u)) >> 16;
  return (unsigned short)u;
}

static __device__ __forceinline__ void gload16(const unsigned short* g, unsigned short* l) {
  __builtin_amdgcn_global_load_lds(
      (const __attribute__((address_space(1))) unsigned int*)g,
      (__attribute__((address_space(3))) unsigned int*)l, 16, 0, 0);
}

#define VMCNT0() asm volatile("s_waitcnt vmcnt(0)" ::: "memory")
#define BARRIER() do { asm volatile("" ::: "memory"); __builtin_amdgcn_s_barrier(); asm volatile("" ::: "memory"); } while (0)

// 128x128 tile, BK=64, 4 waves (2x2), 4x4 16x16x32 bf16 frags.
// LDS: 2 slots per matrix (8192 ushorts each). Row = 8 chunks of 16B;
// chunk c of row r holds global chunk c^(r&7) (pre-swizzled source).
// 2-phase: iter ks stages tile ks+1 into slot^1, computes slot, then
// vmcnt(0)+barrier (the ONLY wait — staging latency hides under compute).
static __device__ __forceinline__ void gemm_loop(
    const unsigned short* __restrict__ A, const unsigned short* __restrict__ Bt,
    int lda, int ldb, int nk, int bi, int bj,
    unsigned short* lA, unsigned short* lB, floatx4 acc[4][4]) {
  const int t = threadIdx.x, wave = t >> 6, lane = t & 63;
  const int wr = wave >> 1, wc = wave & 1;
  const int sr = lane >> 3;
  const int sc = ((lane & 7) ^ sr) * 8;
  const unsigned short* gA = A + (long long)(bi * 128 + wave * 32 + sr) * lda + sc;
  const unsigned short* gB = Bt + (long long)(bj * 128 + wave * 32 + sr) * ldb + sc;
  unsigned short* lAw = lA + wave * 2048;
  unsigned short* lBw = lB + wave * 2048;
  const int frow = lane & 15, hi = lane >> 4;

  // prologue: stage tile 0 into slot 0
#pragma unroll
  for (int g = 0; g < 4; ++g) {
    gload16(gA + (long long)g * 8 * lda, lAw + g * 512);
    gload16(gB + (long long)g * 8 * ldb, lBw + g * 512);
  }
  __syncthreads();

  for (int ks = 0; ks < nk; ++ks) {
    const int cur = (ks & 1) << 13;  // 8192-ushort slots
    const int nxt = cur ^ 8192;
    if (ks + 1 < nk) {
      const long long k0 = (long long)(ks + 1) * 64;
#pragma unroll
      for (int g = 0; g < 4; ++g) {
        gload16(gA + (long long)g * 8 * lda + k0, lAw + nxt + g * 512);
        gload16(gB + (long long)g * 8 * ldb + k0, lBw + nxt + g * 512);
      }
    }
#pragma unroll
    for (int kk = 0; kk < 2; ++kk) {
      const int ch = (kk * 4 + hi) ^ (frow & 7);
      short8 af[4], bf[4];
#pragma unroll
      for (int m = 0; m < 4; ++m)
        af[m] = *(const short8*)&lA[cur + (wr * 64 + m * 16 + frow) * 64 + ch * 8];
#pragma unroll
      for (int n = 0; n < 4; ++n)
        bf[n] = *(const short8*)&lB[cur + (wc * 64 + n * 16 + frow) * 64 + ch * 8];
#pragma unroll
      for (int m = 0; m < 4; ++m)
#pragma unroll
        for (int n = 0; n < 4; ++n)
          acc[m][n] = __builtin_amdgcn_mfma_f32_16x16x32_bf16(af[m], bf[n], acc[m][n], 0, 0, 0);
    }
    if (ks + 1 < nk) { VMCNT0(); }
    BARRIER();
  }
}

#define GEMM_LDS() __shared__ __align__(16) unsigned short lA[16384], lB[16384]

// Gt[j][i] = sum_d Wk[j][d]*Wq[i][d]  (both untransposed bf16), grid (8,8)
__global__ __launch_bounds__(256) void gt_kernel(
    const unsigned short* __restrict__ WkB, const unsigned short* __restrict__ WqB,
    unsigned short* __restrict__ Gt) {
  GEMM_LDS();
  floatx4 acc[4][4] = {};
  gemm_loop(WkB, WqB, 1024, 1024, 16, blockIdx.x, blockIdx.y, lA, lB, acc);
  const int tid = threadIdx.x, wave = tid >> 6, lane = tid & 63;
  const int wr = wave >> 1, wc = wave & 1, frow = lane & 15, hi = lane >> 4;
  const long long crow0 = (long long)blockIdx.x * 128 + wr * 64 + hi * 4;
  const int ccol = blockIdx.y * 128 + wc * 64 + frow;
#pragma unroll
  for (int m = 0; m < 4; ++m)
#pragma unroll
    for (int j = 0; j < 4; ++j) {
      unsigned short* cp = Gt + (crow0 + m * 16 + j) * 1024 + ccol;
#pragma unroll
      for (int n = 0; n < 4; ++n) cp[n * 16] = f2b(acc[m][n][j]);
    }
}

// z=0: T = Xq @ Gt^T-form -> Tb [8192][1024] ; z=1: V^T = Wv^T @ Xv^T -> Vt [1024][8192]
__global__ __launch_bounds__(256) void projTV(
    const unsigned short* __restrict__ Xb, const unsigned short* __restrict__ WvT,
    const unsigned short* __restrict__ Gt, unsigned short* __restrict__ Tb,
    unsigned short* __restrict__ Vt) {
  GEMM_LDS();
  const int z = blockIdx.z;
  const unsigned short *A, *B;
  unsigned short* C;
  int ldc, bi, bj;
  if (z == 0) { A = Xb + XE; B = Gt; C = Tb; ldc = 1024; bi = blockIdx.x; bj = blockIdx.y; }
  else        { A = WvT;     B = Xb; C = Vt; ldc = 8192; bi = blockIdx.y; bj = blockIdx.x; }
  floatx4 acc[4][4] = {};
  gemm_loop(A, B, 1024, 1024, 16, bi, bj, lA, lB, acc);
  const int tid = threadIdx.x, wave = tid >> 6, lane = tid & 63;
  const int wr = wave >> 1, wc = wave & 1, frow = lane & 15, hi = lane >> 4;
  const long long crow0 = (long long)bi * 128 + wr * 64 + hi * 4;
  const int ccol = bj * 128 + wc * 64 + frow;
#pragma unroll
  for (int m = 0; m < 4; ++m)
#pragma unroll
    for (int j = 0; j < 4; ++j) {
      unsigned short* cp = C + (crow0 + m * 16 + j) * (long long)ldc + ccol;
#pragma unroll
      for (int n = 0; n < 4; ++n) cp[n * 16] = f2b(acc[m][n][j]);
    }
}

// 1-D grid 544: XCD-bijective remap (544 = 8*68, each XCD gets half a batch's
// triangle), then quad-supertile bj-major tri decode for L2 panel reuse.
// S-tile = T·Xk^T ; P = exp(S/32) bf16 (causal) ; row-sum partials -> Rpart.
__global__ __launch_bounds__(256) void scores_exp(
    const unsigned short* __restrict__ Tb, const unsigned short* __restrict__ Xk,
    unsigned short* __restrict__ P, float* __restrict__ Rpart) {
  GEMM_LDS();
  const int orig = blockIdx.x;
  const int w = (orig & 7) * 68 + (orig >> 3);  // bijective: 544 = 8*68
  const int b = w / 136;
  int rem = w - b * 136;
  int g = 0;
  while (rem >= 16 * g + 10) { rem -= 16 * g + 10; ++g; }  // quad rows 4g..4g+3
  int bi, bj;
  if (rem < (4 * g + 1) * 4) { bj = rem >> 2; bi = 4 * g + (rem & 3); }
  else {
    const int v = rem - (4 * g + 1) * 4;  // runs 3,2,1 for bj=4g+1..4g+3
    if (v < 3)      { bj = 4 * g + 1; bi = 4 * g + 1 + v; }
    else if (v < 5) { bj = 4 * g + 2; bi = 4 * g + 2 + (v - 3); }
    else            { bj = 4 * g + 3; bi = 4 * g + 3; }
  }

  floatx4 acc[4][4] = {};
  gemm_loop(Tb + (long long)b * 2048 * 1024, Xk + (long long)b * 2048 * 1024,
            1024, 1024, 16, bi, bj, lA, lB, acc);

  const int tid = threadIdx.x, wave = tid >> 6, lane = tid & 63;
  const int wr = wave >> 1, wc = wave & 1, frow = lane & 15, hi = lane >> 4;
  const bool diag = (bi == bj);
  float rp[4][4];
#pragma unroll
  for (int m = 0; m < 4; ++m)
#pragma unroll
    for (int j = 0; j < 4; ++j) {
      const int r = wr * 64 + hi * 4 + m * 16 + j;
      float s = 0.f;
#pragma unroll
      for (int n = 0; n < 4; ++n) {
        const int c = wc * 64 + frow + n * 16;
        float e = __expf(acc[m][n][j] * 0.03125f);
        if (diag && c > r) e = 0.f;
        acc[m][n][j] = e;
        s += e;
      }
      rp[m][j] = s;
    }
#pragma unroll
  for (int m = 0; m < 4; ++m)
#pragma unroll
    for (int j = 0; j < 4; ++j) {
      rp[m][j] += __shfl_xor(rp[m][j], 1);
      rp[m][j] += __shfl_xor(rp[m][j], 2);
      rp[m][j] += __shfl_xor(rp[m][j], 4);
      rp[m][j] += __shfl_xor(rp[m][j], 8);
    }
  unsigned short* C = P + (long long)b * 2048 * 2048;
  const long long crow0 = (long long)bi * 128 + wr * 64 + hi * 4;
  const int ccol = bj * 128 + wc * 64 + frow;
#pragma unroll
  for (int m = 0; m < 4; ++m)
#pragma unroll
    for (int j = 0; j < 4; ++j) {
      unsigned short* cp = C + (crow0 + m * 16 + j) * 2048LL + ccol;
#pragma unroll
      for (int n = 0; n < 4; ++n) cp[n * 16] = f2b(acc[m][n][j]);
    }
  __syncthreads();
  float* red = (float*)lA;
  if (frow == 0) {
#pragma unroll
    for (int m = 0; m < 4; ++m)
#pragma unroll
      for (int j = 0; j < 4; ++j)
        red[(wr * 64 + hi * 4 + m * 16 + j) * 2 + wc] = rp[m][j];
  }
  __syncthreads();
  if (tid < 128)
    Rpart[((long long)b * 16 + bj) * 2048 + bi * 128 + tid] = red[tid * 2] + red[tid * 2 + 1];
}

// Rinv[b][row] = 1 / sum_{bj<=row>>7} Rpart[b][bj][row]
__global__ __launch_bounds__(256) void rowsum(
    const float* __restrict__ Rpart, float* __restrict__ Rinv) {
  const int t = blockIdx.x * 256 + threadIdx.x;  // 0..8191
  const int b = t >> 11, row = t & 2047;
  const int nb = (row >> 7) + 1;
  float s = 0.f;
  for (int bj = 0; bj < nb; ++bj) s += Rpart[(b * 16 + bj) * 2048 + row];
  Rinv[t] = 1.f / s;
}

// O = (P V) * Rinv ; grid 512 (all-resident at 2 blocks/CU), heavy+light pairing.
__global__ __launch_bounds__(256) void pv_kernel(
    const unsigned short* __restrict__ P, const unsigned short* __restrict__ Vt,
    const float* __restrict__ Rinv, float* __restrict__ out) {
  GEMM_LDS();
  const int c = blockIdx.x;
  const int t = (c < 256) ? c : 767 - c;
  const int bi = 15 - (t >> 5);
  const int sub = t & 31;
  const int b = sub >> 3, bj = sub & 7;
  floatx4 acc[4][4] = {};
  gemm_loop(P + (long long)b * 2048 * 2048, Vt + (long long)b * 2048, 2048, 8192,
            (bi + 1) * 2, bi, bj, lA, lB, acc);
  const int tid = threadIdx.x, wave = tid >> 6, lane = tid & 63;
  const int wr = wave >> 1, wc = wave & 1, frow = lane & 15, hi = lane >> 4;
  float* C = out + (long long)b * 2048 * 1024;
  const float* Ri = Rinv + b * 2048;
#pragma unroll
  for (int m = 0; m < 4; ++m)
#pragma unroll
    for (int j = 0; j < 4; ++j) {
      const int row = bi * 128 + wr * 64 + hi * 4 + m * 16 + j;
      const float riv = Ri[row];
      float* cp = C + (long long)row * 1024 + bj * 128 + wc * 64 + frow;
#pragma unroll
      for (int n = 0; n < 4; ++n) cp[n * 16] = acc[m][n][j] * riv;
    }
}

// fp32->bf16 converts: X's (grid 1024,3): y0 Xv, y1 Xq, y2 Xk
__global__ __launch_bounds__(256) void cvtX(
    const float* __restrict__ Xk, const float* __restrict__ Xv,
    const float* __restrict__ Xq, unsigned short* __restrict__ Xb) {
  const float* in = blockIdx.y == 0 ? Xv : (blockIdx.y == 1 ? Xq : Xk);
  unsigned short* o = Xb + (long long)blockIdx.y * XE;
  const int n4 = (int)(XE / 4);
  const int stride = 1024 * 256;
  for (int i = blockIdx.x * 256 + threadIdx.x; i < n4; i += stride) {
    float4 x = ((const float4*)in)[i];
    ushort4 v;
    v.x = f2b(x.x); v.y = f2b(x.y); v.z = f2b(x.z); v.w = f2b(x.w);
    ((ushort4*)o)[i] = v;
  }
}

// Wq, Wk plain converts (grid 128,2): y0 Wq, y1 Wk
__global__ __launch_bounds__(256) void cvtW(
    const float* __restrict__ Wq, const float* __restrict__ Wk,
    unsigned short* __restrict__ WqB, unsigned short* __restrict__ WkB) {
  const float* in = blockIdx.y == 0 ? Wq : Wk;
  unsigned short* o = blockIdx.y == 0 ? WqB : WkB;
  const int n4 = (int)(WE / 4);
  const int stride = 128 * 256;
  for (int i = blockIdx.x * 256 + threadIdx.x; i < n4; i += stride) {
    float4 x = ((const float4*)in)[i];
    ushort4 v;
    v.x = f2b(x.x); v.y = f2b(x.y); v.z = f2b(x.z); v.w = f2b(x.w);
    ((ushort4*)o)[i] = v;
  }
}

// Wv [i][o] fp32 -> WvT bf16 [o][i], grid (16,16)
__global__ __launch_bounds__(256) void wcvtV(
    const float* __restrict__ Wv, unsigned short* __restrict__ WvT) {
  __shared__ unsigned short tile[64][65];
  const int t = threadIdx.x;
  const int i0 = blockIdx.x * 64, j0 = blockIdx.y * 64;
#pragma unroll
  for (int r = 0; r < 16; ++r) {
    int lin = r * 256 + t;
    int i = lin >> 6, j = lin & 63;
    tile[i][j] = f2b(Wv[(long long)(i0 + i) * 1024 + j0 + j]);
  }
  __syncthreads();
#pragma unroll
  for (int r = 0; r < 16; ++r) {
    int lin = r * 256 + t;
    int o = lin >> 6, i = lin & 63;
    WvT[(long long)(j0 + o) * 1024 + i0 + i] = tile[i][o];
  }
}

extern "C" void kernel_launch(void* const* d_in, const int* in_sizes, int n_in,
                              void* d_out, int out_size, void* d_ws, size_t ws_size,
                              hipStream_t stream) {
  const float* Xk = (const float*)d_in[0];
  const float* Xv = (const float*)d_in[1];
  const float* Xq = (const float*)d_in[2];
  const float* Wk = (const float*)d_in[3];
  const float* Wv = (const float*)d_in[4];
  const float* Wq = (const float*)d_in[5];
  float* out = (float*)d_out;

  // ws (ushort elems): Xb[3XE: Xv|Xq|Xk] WqB[WE] WkB[WE] WvT[WE] Gt[WE]
  //                    Tb[XE] Vt[XE] Rpart[262144] Rinv[16384]
  // Pbuf (bf16 P, 2XE) aliases Xv|Xq (dead after projTV).
  unsigned short* ws = (unsigned short*)d_ws;
  unsigned short* Xb = ws;
  unsigned short* WqB = ws + 3 * XE;
  unsigned short* WkB = WqB + WE;
  unsigned short* WvT = WkB + WE;
  unsigned short* Gt = WvT + WE;
  unsigned short* Tb = Gt + WE;
  unsigned short* Vt = Tb + XE;
  float* Rpart = (float*)(Vt + XE);
  float* Rinv = Rpart + 131072;
  unsigned short* Pbuf = ws;  // alias

  cvtX<<<dim3(1024, 3), 256, 0, stream>>>(Xk, Xv, Xq, Xb);
  cvtW<<<dim3(128, 2), 256, 0, stream>>>(Wq, Wk, WqB, WkB);
  wcvtV<<<dim3(16, 16), 256, 0, stream>>>(Wv, WvT);
  gt_kernel<<<dim3(8, 8), 256, 0, stream>>>(WkB, WqB, Gt);
  projTV<<<dim3(64, 8, 2), 256, 0, stream>>>(Xb, WvT, Gt, Tb, Vt);
  scores_exp<<<544, 256, 0, stream>>>(Tb, Xb + 2 * XE, Pbuf, Rpart);
  rowsum<<<32, 256, 0, stream>>>(Rpart, Rinv);
  pv_kernel<<<512, 256, 0, stream>>>(Pbuf, Vt, Rinv, out);
}

// Round 7
// 179.484 us; speedup vs baseline: 1.0817x; 1.0513x over previous
//
#include <hip/hip_runtime.h>

// AttentionHead: B=4, S=2048, D=1024, fp32 in/out, bf16 MFMA compute.
// G = Wq·Wk^T  =>  S = Xq·G·Xk^T (K-projection eliminated).
// Max-free softmax: P = exp(S/32) fused into scores epilogue + row-sum partials;
// PV scales by 1/rowsum.
// GEMM core: single-buffer BK=64, 2-barrier (R2/R5-proven), templated on
// NFRAG (B-tile 128 or 64 wide). Occupancy via grid shaping: every GEMM
// dispatch >= 1024 blocks (~4+ blocks/CU). XCD-bijective block swizzle.

typedef __attribute__((ext_vector_type(8))) short short8;
typedef __attribute__((ext_vector_type(4))) float floatx4;

static constexpr long long XE = 8388608LL;  // 4*2048*1024
static constexpr long long WE = 1048576LL;  // 1024*1024

static __device__ __forceinline__ unsigned short f2b(float f) {
  unsigned u = __builtin_bit_cast(unsigned, f);
  u = (u + 0x7fffu + ((u >> 16) & 1u)) >> 16;
  return (unsigned short)u;
}

static __device__ __forceinline__ void gload16(const unsigned short* g, unsigned short* l) {
  __builtin_amdgcn_global_load_lds(
      (const __attribute__((address_space(1))) unsigned int*)g,
      (__attribute__((address_space(3))) unsigned int*)l, 16, 0, 0);
}

// Tile: 128 x (NF*32), BK=64, 4 waves (2x2), wave-tile 64 x (NF*16).
// LDS row = 8 chunks of 16B; chunk c of row r holds global chunk c^(r&7)
// (pre-swizzled global source, linear gload dest, swizzled read).
template <int NF>
static __device__ __forceinline__ void gemm_loop(
    const unsigned short* __restrict__ A, const unsigned short* __restrict__ Bt,
    int lda, int ldb, int nk, int bi, int bj,
    unsigned short* lA, unsigned short* lB, floatx4 acc[4][NF]) {
  const int t = threadIdx.x, wave = t >> 6, lane = t & 63;
  const int wr = wave >> 1, wc = wave & 1;
  const int sr = lane >> 3;
  const int sc = ((lane & 7) ^ sr) * 8;
  const unsigned short* gA = A + (long long)(bi * 128 + wave * 32 + sr) * lda + sc;
  const unsigned short* gB = Bt + (long long)(bj * (NF * 32) + wave * (NF * 8) + sr) * ldb + sc;
  unsigned short* lAw = lA + wave * 2048;
  unsigned short* lBw = lB + wave * (NF * 512);
  const int frow = lane & 15, hi = lane >> 4;

  for (int ks = 0; ks < nk; ++ks) {
    const long long k0 = (long long)ks * 64;
    __syncthreads();
#pragma unroll
    for (int g = 0; g < 4; ++g)
      gload16(gA + (long long)g * 8 * lda + k0, lAw + g * 512);
#pragma unroll
    for (int g = 0; g < NF; ++g)
      gload16(gB + (long long)g * 8 * ldb + k0, lBw + g * 512);
    __syncthreads();
#pragma unroll
    for (int kk = 0; kk < 2; ++kk) {
      const int ch = (kk * 4 + hi) ^ (frow & 7);
      short8 af[4], bf[NF];
#pragma unroll
      for (int m = 0; m < 4; ++m)
        af[m] = *(const short8*)&lA[(wr * 64 + m * 16 + frow) * 64 + ch * 8];
#pragma unroll
      for (int n = 0; n < NF; ++n)
        bf[n] = *(const short8*)&lB[(wc * (NF * 16) + n * 16 + frow) * 64 + ch * 8];
#pragma unroll
      for (int m = 0; m < 4; ++m)
#pragma unroll
        for (int n = 0; n < NF; ++n)
          acc[m][n] = __builtin_amdgcn_mfma_f32_16x16x32_bf16(af[m], bf[n], acc[m][n], 0, 0, 0);
    }
  }
}

// Gt[j][i] = sum_d Wk[j][d]*Wq[i][d]  (both untransposed bf16), grid (8,8)
__global__ __launch_bounds__(256) void gt_kernel(
    const unsigned short* __restrict__ WkB, const unsigned short* __restrict__ WqB,
    unsigned short* __restrict__ Gt) {
  __shared__ __align__(16) unsigned short lA[8192], lB[8192];
  floatx4 acc[4][4] = {};
  gemm_loop<4>(WkB, WqB, 1024, 1024, 16, blockIdx.x, blockIdx.y, lA, lB, acc);
  const int tid = threadIdx.x, wave = tid >> 6, lane = tid & 63;
  const int wr = wave >> 1, wc = wave & 1, frow = lane & 15, hi = lane >> 4;
  const long long crow0 = (long long)blockIdx.x * 128 + wr * 64 + hi * 4;
  const int ccol = blockIdx.y * 128 + wc * 64 + frow;
#pragma unroll
  for (int m = 0; m < 4; ++m)
#pragma unroll
    for (int j = 0; j < 4; ++j) {
      unsigned short* cp = Gt + (crow0 + m * 16 + j) * 1024 + ccol;
#pragma unroll
      for (int n = 0; n < 4; ++n) cp[n * 16] = f2b(acc[m][n][j]);
    }
}

// 1-D grid 1024, XCD-swizzled. jobs 0..511: T = Xq@Gt-form -> Tb [8192][1024];
// jobs 512..1023: V^T = Wv^T @ Xv^T -> Vt [1024][8192].
__global__ __launch_bounds__(256) void projTV(
    const unsigned short* __restrict__ Xb, const unsigned short* __restrict__ WvT,
    const unsigned short* __restrict__ Gt, unsigned short* __restrict__ Tb,
    unsigned short* __restrict__ Vt) {
  __shared__ __align__(16) unsigned short lA[8192], lB[8192];
  const int orig = blockIdx.x;
  const int w = (orig & 7) * 128 + (orig >> 3);  // 1024 = 8*128
  const unsigned short *A, *B;
  unsigned short* C;
  int ldc, bi, bj;
  if (w < 512) { A = Xb + XE; B = Gt; C = Tb; ldc = 1024; bi = w >> 3; bj = w & 7; }
  else { const int j = w - 512; A = WvT; B = Xb; C = Vt; ldc = 8192; bi = j & 7; bj = j >> 3; }
  floatx4 acc[4][4] = {};
  gemm_loop<4>(A, B, 1024, 1024, 16, bi, bj, lA, lB, acc);
  const int tid = threadIdx.x, wave = tid >> 6, lane = tid & 63;
  const int wr = wave >> 1, wc = wave & 1, frow = lane & 15, hi = lane >> 4;
  const long long crow0 = (long long)bi * 128 + wr * 64 + hi * 4;
  const int ccol = bj * 128 + wc * 64 + frow;
#pragma unroll
  for (int m = 0; m < 4; ++m)
#pragma unroll
    for (int j = 0; j < 4; ++j) {
      unsigned short* cp = C + (crow0 + m * 16 + j) * (long long)ldc + ccol;
#pragma unroll
      for (int n = 0; n < 4; ++n) cp[n * 16] = f2b(acc[m][n][j]);
    }
}

// 1-D grid 1088 (=8*136, XCD-swizzled). 128x64 tiles, per batch 272 tri tiles
// (bi in 0..15, bj in 0..2bi+1). S-tile = T·Xk^T ; P = exp(S/32) bf16 (causal) ;
// row-sum partials -> Rpart[b][bj64][2048].
__global__ __launch_bounds__(256) void scores_exp(
    const unsigned short* __restrict__ Tb, const unsigned short* __restrict__ Xk,
    unsigned short* __restrict__ P, float* __restrict__ Rpart) {
  __shared__ __align__(16) unsigned short lA[8192], lB[4096];
  const int orig = blockIdx.x;
  const int w = (orig & 7) * 136 + (orig >> 3);
  const int b = w / 272;
  int t2 = w - b * 272;
  int bi = 0;
  while (t2 >= 2 * bi + 2) { t2 -= 2 * bi + 2; ++bi; }
  const int bj = t2;

  floatx4 acc[4][2] = {};
  gemm_loop<2>(Tb + (long long)b * 2048 * 1024, Xk + (long long)b * 2048 * 1024,
               1024, 1024, 16, bi, bj, lA, lB, acc);

  const int tid = threadIdx.x, wave = tid >> 6, lane = tid & 63;
  const int wr = wave >> 1, wc = wave & 1, frow = lane & 15, hi = lane >> 4;
  const bool diag = (bj >= 2 * bi);
  float rp[4][4];
#pragma unroll
  for (int m = 0; m < 4; ++m)
#pragma unroll
    for (int j = 0; j < 4; ++j) {
      const int rloc = wr * 64 + hi * 4 + m * 16 + j;
      const int rglob = bi * 128 + rloc;
      float s = 0.f;
#pragma unroll
      for (int n = 0; n < 2; ++n) {
        const int cglob = bj * 64 + wc * 32 + n * 16 + frow;
        float e = __expf(acc[m][n][j] * 0.03125f);
        if (diag && cglob > rglob) e = 0.f;
        acc[m][n][j] = e;
        s += e;
      }
      rp[m][j] = s;
    }
#pragma unroll
  for (int m = 0; m < 4; ++m)
#pragma unroll
    for (int j = 0; j < 4; ++j) {
      rp[m][j] += __shfl_xor(rp[m][j], 1);
      rp[m][j] += __shfl_xor(rp[m][j], 2);
      rp[m][j] += __shfl_xor(rp[m][j], 4);
      rp[m][j] += __shfl_xor(rp[m][j], 8);
    }
  unsigned short* C = P + (long long)b * 2048 * 2048;
  const long long crow0 = (long long)bi * 128 + wr * 64 + hi * 4;
  const int ccol = bj * 64 + wc * 32 + frow;
#pragma unroll
  for (int m = 0; m < 4; ++m)
#pragma unroll
    for (int j = 0; j < 4; ++j) {
      unsigned short* cp = C + (crow0 + m * 16 + j) * 2048LL + ccol;
      cp[0] = f2b(acc[m][0][j]);
      cp[16] = f2b(acc[m][1][j]);
    }
  __syncthreads();
  float* red = (float*)lA;
  if (frow == 0) {
#pragma unroll
    for (int m = 0; m < 4; ++m)
#pragma unroll
      for (int j = 0; j < 4; ++j)
        red[(wr * 64 + hi * 4 + m * 16 + j) * 2 + wc] = rp[m][j];
  }
  __syncthreads();
  if (tid < 128)
    Rpart[((long long)b * 32 + bj) * 2048 + bi * 128 + tid] = red[tid * 2] + red[tid * 2 + 1];
}

// Rinv[b][row] = 1 / sum_{bj64 <= row>>6} Rpart[b][bj64][row]
__global__ __launch_bounds__(256) void rowsum(
    const float* __restrict__ Rpart, float* __restrict__ Rinv) {
  const int t = blockIdx.x * 256 + threadIdx.x;  // 0..8191
  const int b = t >> 11, row = t & 2047;
  const int nb = (row >> 6) + 1;
  float s = 0.f;
  for (int bj = 0; bj < nb; ++bj) s += Rpart[(b * 32 + bj) * 2048 + row];
  Rinv[t] = 1.f / s;
}

// O = (P V) * Rinv ; 1-D grid 1024 (=8*128, XCD-swizzled), 128x64 tiles,
// heavy+light pairing: consecutive w pairs get bi = {p, 15-p} (const total K).
__global__ __launch_bounds__(256) void pv_kernel(
    const unsigned short* __restrict__ P, const unsigned short* __restrict__ Vt,
    const float* __restrict__ Rinv, float* __restrict__ out) {
  __shared__ __align__(16) unsigned short lA[8192], lB[4096];
  const int orig = blockIdx.x;
  const int w = (orig & 7) * 128 + (orig >> 3);
  const int tt = w >> 1, s = w & 1;
  const int p = tt & 7;
  const int bi = s ? 15 - p : p;
  const int b = (tt >> 3) & 3;
  const int bj = tt >> 5;  // 0..15 (64-wide d-tiles)
  floatx4 acc[4][2] = {};
  gemm_loop<2>(P + (long long)b * 2048 * 2048, Vt + (long long)b * 2048, 2048, 8192,
               (bi + 1) * 2, bi, bj, lA, lB, acc);
  const int tid = threadIdx.x, wave = tid >> 6, lane = tid & 63;
  const int wr = wave >> 1, wc = wave & 1, frow = lane & 15, hi = lane >> 4;
  float* C = out + (long long)b * 2048 * 1024;
  const float* Ri = Rinv + b * 2048;
#pragma unroll
  for (int m = 0; m < 4; ++m)
#pragma unroll
    for (int j = 0; j < 4; ++j) {
      const int row = bi * 128 + wr * 64 + hi * 4 + m * 16 + j;
      const float riv = Ri[row];
      float* cp = C + (long long)row * 1024 + bj * 64 + wc * 32 + frow;
      cp[0] = acc[m][0][j] * riv;
      cp[16] = acc[m][1][j] * riv;
    }
}

// All fp32->bf16 converts in ONE dispatch (3584 blocks):
//   [0,3072): Xv,Xq,Xk -> Xb ; [3072,3328): Wq,Wk plain ; [3328,3584): Wv transpose.
__global__ __launch_bounds__(256) void cvtAll(
    const float* __restrict__ Xk, const float* __restrict__ Xv,
    const float* __restrict__ Xq, const float* __restrict__ Wq,
    const float* __restrict__ Wk, const float* __restrict__ Wv,
    unsigned short* __restrict__ Xb, unsigned short* __restrict__ WqB,
    unsigned short* __restrict__ WkB, unsigned short* __restrict__ WvT) {
  __shared__ unsigned short tile[64][65];
  const int bx = blockIdx.x, t = threadIdx.x;
  if (bx < 3072) {
    const int y = bx >> 10, sub = bx & 1023;
    const float* in = y == 0 ? Xv : (y == 1 ? Xq : Xk);
    unsigned short* o = Xb + (long long)y * XE;
    const int n4 = (int)(XE / 4), stride = 1024 * 256;
    for (int i = sub * 256 + t; i < n4; i += stride) {
      float4 x = ((const float4*)in)[i];
      ushort4 v;
      v.x = f2b(x.x); v.y = f2b(x.y); v.z = f2b(x.z); v.w = f2b(x.w);
      ((ushort4*)o)[i] = v;
    }
  } else if (bx < 3328) {
    const int w2 = bx - 3072;
    const int y = w2 >> 7, sub = w2 & 127;
    const float* in = y == 0 ? Wq : Wk;
    unsigned short* o = y == 0 ? WqB : WkB;
    const int n4 = (int)(WE / 4), stride = 128 * 256;
    for (int i = sub * 256 + t; i < n4; i += stride) {
      float4 x = ((const float4*)in)[i];
      ushort4 v;
      v.x = f2b(x.x); v.y = f2b(x.y); v.z = f2b(x.z); v.w = f2b(x.w);
      ((ushort4*)o)[i] = v;
    }
  } else {
    const int v = bx - 3328;
    const int i0 = (v & 15) * 64, j0 = (v >> 4) * 64;
#pragma unroll
    for (int r = 0; r < 16; ++r) {
      int lin = r * 256 + t;
      int i = lin >> 6, j = lin & 63;
      tile[i][j] = f2b(Wv[(long long)(i0 + i) * 1024 + j0 + j]);
    }
    __syncthreads();
#pragma unroll
    for (int r = 0; r < 16; ++r) {
      int lin = r * 256 + t;
      int o = lin >> 6, i = lin & 63;
      WvT[(long long)(j0 + o) * 1024 + i0 + i] = tile[i][o];
    }
  }
}

extern "C" void kernel_launch(void* const* d_in, const int* in_sizes, int n_in,
                              void* d_out, int out_size, void* d_ws, size_t ws_size,
                              hipStream_t stream) {
  const float* Xk = (const float*)d_in[0];
  const float* Xv = (const float*)d_in[1];
  const float* Xq = (const float*)d_in[2];
  const float* Wk = (const float*)d_in[3];
  const float* Wv = (const float*)d_in[4];
  const float* Wq = (const float*)d_in[5];
  float* out = (float*)d_out;

  // ws (ushort elems): Xb[3XE: Xv|Xq|Xk] WqB[WE] WkB[WE] WvT[WE] Gt[WE]
  //                    Tb[XE] Vt[XE] Rpart[4*32*2048 f32] Rinv[8192 f32]  ~94 MB
  // Pbuf (bf16 P, 2XE) aliases Xv|Xq ONLY (both dead after projTV; Xk at
  // Xb+2XE stays live for scores and is NOT overlapped).
  unsigned short* ws = (unsigned short*)d_ws;
  unsigned short* Xb = ws;
  unsigned short* WqB = ws + 3 * XE;
  unsigned short* WkB = WqB + WE;
  unsigned short* WvT = WkB + WE;
  unsigned short* Gt = WvT + WE;
  unsigned short* Tb = Gt + WE;
  unsigned short* Vt = Tb + XE;
  float* Rpart = (float*)(Vt + XE);
  float* Rinv = Rpart + 4 * 32 * 2048;
  unsigned short* Pbuf = ws;  // alias over Xv|Xq

  cvtAll<<<3584, 256, 0, stream>>>(Xk, Xv, Xq, Wq, Wk, Wv, Xb, WqB, WkB, WvT);
  gt_kernel<<<dim3(8, 8), 256, 0, stream>>>(WkB, WqB, Gt);
  projTV<<<1024, 256, 0, stream>>>(Xb, WvT, Gt, Tb, Vt);
  scores_exp<<<1088, 256, 0, stream>>>(Tb, Xb + 2 * XE, Pbuf, Rpart);
  rowsum<<<32, 256, 0, stream>>>(Rpart, Rinv);
  pv_kernel<<<1024, 256, 0, stream>>>(Pbuf, Vt, Rinv, out);
}

// Round 8
// 169.880 us; speedup vs baseline: 1.1428x; 1.0565x over previous
//
#include <hip/hip_runtime.h>

// AttentionHead: B=4, S=2048, D=1024, fp32 in/out, bf16 MFMA compute.
// G = Wq·Wk^T  =>  S = Xq·G·Xk^T (K-projection eliminated).
// Max-free softmax: P = exp(S/32) fused into scores epilogue + row-sum partials;
// PV scales by 1/rowsum.
// projTV: 256x256 8-phase pipelined core (R4-verified), 256 blocks = exactly
// one machine round. scores/pv/gt: single-buffer BK=64 2-barrier core.

typedef __attribute__((ext_vector_type(8))) short short8;
typedef __attribute__((ext_vector_type(4))) float floatx4;

static constexpr long long XE = 8388608LL;  // 4*2048*1024
static constexpr long long WE = 1048576LL;  // 1024*1024

static __device__ __forceinline__ unsigned short f2b(float f) {
  unsigned u = __builtin_bit_cast(unsigned, f);
  u = (u + 0x7fffu + ((u >> 16) & 1u)) >> 16;
  return (unsigned short)u;
}

static __device__ __forceinline__ void gload16(const unsigned short* g, unsigned short* l) {
  __builtin_amdgcn_global_load_lds(
      (const __attribute__((address_space(1))) unsigned int*)g,
      (__attribute__((address_space(3))) unsigned int*)l, 16, 0, 0);
}

#define VMCNT(n) asm volatile("s_waitcnt vmcnt(" #n ")" ::: "memory")
#define LGKM0() asm volatile("s_waitcnt lgkmcnt(0)" ::: "memory")
#define BARRIER() do { asm volatile("" ::: "memory"); __builtin_amdgcn_s_barrier(); asm volatile("" ::: "memory"); } while (0)

// ============ projTV: 256x256, BK=64x2, 8-wave, 8-phase (R4 core) ============
// LDS slot s (64KB): A-tile [s*65536, +32768), B-tile next 32768.
// Row = 128B = 8 chunks of 16B; LDS chunk p of row r holds global chunk p^(r&7).

#define STAGE(base, matoff, h, slot, kt) do {                                  \
    const unsigned short* _s = (base) + (h) * 131072 + (kt) * 64;              \
    char* _d = sb + (slot) * 65536 + (matoff) + (h) * 16384 + dwave;           \
    gload16(_s, (unsigned short*)_d);                                          \
    gload16(_s + 65536, (unsigned short*)(_d + 8192));                         \
  } while (0)

#define READ_A(slot, mb) do {                                                  \
    const char* _p = sb + (slot) * 65536 + aoffb + (mb) * 2048;                \
    af[0][0] = *(const short8*)(_p + c0);        af[0][1] = *(const short8*)(_p + c1); \
    af[1][0] = *(const short8*)(_p + 2048 + c0); af[1][1] = *(const short8*)(_p + 2048 + c1); \
    af[2][0] = *(const short8*)(_p + 4096 + c0); af[2][1] = *(const short8*)(_p + 4096 + c1); \
    af[3][0] = *(const short8*)(_p + 6144 + c0); af[3][1] = *(const short8*)(_p + 6144 + c1); \
  } while (0)

#define READ_B(slot, nb, bfx) do {                                             \
    const char* _p = sb + (slot) * 65536 + boffb + (nb) * 2048;                \
    bfx[0][0] = *(const short8*)(_p + c0);        bfx[0][1] = *(const short8*)(_p + c1); \
    bfx[1][0] = *(const short8*)(_p + 2048 + c0); bfx[1][1] = *(const short8*)(_p + 2048 + c1); \
  } while (0)

#define MF16(MB, NB, bfx) do {                                                 \
    __builtin_amdgcn_s_setprio(1);                                             \
    _Pragma("unroll")                                                          \
    for (int _m = 0; _m < 4; ++_m) {                                           \
      _Pragma("unroll")                                                        \
      for (int _n = 0; _n < 2; ++_n) {                                         \
        acc[(MB) + _m][(NB) + _n] = __builtin_amdgcn_mfma_f32_16x16x32_bf16(   \
            af[_m][0], bfx[_n][0], acc[(MB) + _m][(NB) + _n], 0, 0, 0);        \
        acc[(MB) + _m][(NB) + _n] = __builtin_amdgcn_mfma_f32_16x16x32_bf16(   \
            af[_m][1], bfx[_n][1], acc[(MB) + _m][(NB) + _n], 0, 0, 0);        \
      } }                                                                      \
    __builtin_amdgcn_s_setprio(0);                                             \
  } while (0)

// 1-D grid 256 (=8*32, XCD-chunked). w<128: T = Xq@Gt-form (bi=w>>2, bj=w&3);
// w>=128: V^T = Wv^T @ Xv^T (bi=j&3, bj=j>>2).
__global__ __launch_bounds__(512, 2) void projTV8(
    const unsigned short* __restrict__ Xb, const unsigned short* __restrict__ WvT,
    const unsigned short* __restrict__ Gt, unsigned short* __restrict__ Tb,
    unsigned short* __restrict__ Vt) {
  extern __shared__ char sb[];
  const int orig = blockIdx.x;
  const int w = (orig & 7) * 32 + (orig >> 3);  // 256 = 8*32
  const unsigned short *Aop, *Bop;
  unsigned short* C;
  int ldc, bi, bj;
  if (w < 128) { Aop = Xb + XE; Bop = Gt; C = Tb; ldc = 1024; bi = w >> 2; bj = w & 3; }
  else { const int j = w - 128; Aop = WvT; Bop = Xb; C = Vt; ldc = 8192; bi = j & 3; bj = j >> 2; }

  const int tid = threadIdx.x, wave = tid >> 6, lane = tid & 63;
  const int wm = wave >> 2, wn = wave & 3, frow = lane & 15, hi = lane >> 4;
  const int r0 = tid >> 3, p0 = ((tid & 7) ^ (r0 & 7)) * 8;
  const int dwave = wave * 1024;
  const int sx = frow & 7;
  const int c0 = (hi ^ sx) * 16, c1 = ((4 + hi) ^ sx) * 16;
  const int aoffb = (wm * 128 + frow) * 128;
  const int boffb = 32768 + (wn * 64 + frow) * 128;
  const unsigned short* Ab = Aop + (long long)(bi * 256 + r0) * 1024 + p0;
  const unsigned short* Bb = Bop + (long long)(bj * 256 + r0) * 1024 + p0;

  short8 af[4][2], bf0[2][2], bf1[2][2];
  floatx4 acc[8][4] = {};

  // prologue: As0 h0,h1 (kt0) ; Bs0 h0,h1 (kt0) ; Bs1 h0,h1 (kt1)
  STAGE(Ab, 0, 0, 0, 0);     STAGE(Ab, 0, 1, 0, 0);
  STAGE(Bb, 32768, 0, 0, 0); STAGE(Bb, 32768, 1, 0, 0);
  STAGE(Bb, 32768, 0, 1, 1); STAGE(Bb, 32768, 1, 1, 1);
  VMCNT(4);
  BARRIER();

  for (int t = 0; t < 8; ++t) {
    const int kt1 = 2 * t + 1, kt2 = 2 * t + 2, kt3 = 2 * t + 3;
    const bool pf = t < 7;
    // ph1: (m0-3, n0-1) slot0 ; prefetch A-slot1 h0 (kt1)
    READ_A(0, 0); READ_B(0, 0, bf0);
    STAGE(Ab, 0, 0, 1, kt1);
    BARRIER(); LGKM0();
    MF16(0, 0, bf0);
    BARRIER();
    // ph2: (m0-3, n2-3) ; prefetch A-slot1 h1
    READ_B(0, 2, bf1);
    STAGE(Ab, 0, 1, 1, kt1);
    BARRIER(); LGKM0();
    MF16(0, 2, bf1);
    BARRIER();
    // ph3: (m4-7, n2-3) ; prefetch B-slot0 h0 (kt2)
    READ_A(0, 4);
    if (pf) STAGE(Bb, 32768, 0, 0, kt2);
    BARRIER(); LGKM0();
    MF16(4, 2, bf1);
    BARRIER();
    // ph4: (m4-7, n0-1, reuse) ; prefetch B-slot0 h1 ; counted vmcnt
    if (pf) STAGE(Bb, 32768, 1, 0, kt2);
    BARRIER();
    MF16(4, 0, bf0);
    if (pf) { VMCNT(4); } else { VMCNT(0); }
    BARRIER();
    // ph5: slot1 (m0-3, n0-1) ; prefetch A-slot0 h0 (kt2)
    READ_A(1, 0); READ_B(1, 0, bf0);
    if (pf) STAGE(Ab, 0, 0, 0, kt2);
    BARRIER(); LGKM0();
    MF16(0, 0, bf0);
    BARRIER();
    // ph6: (m0-3, n2-3) ; prefetch A-slot0 h1
    READ_B(1, 2, bf1);
    if (pf) STAGE(Ab, 0, 1, 0, kt2);
    BARRIER(); LGKM0();
    MF16(0, 2, bf1);
    BARRIER();
    // ph7: (m4-7, n2-3) ; prefetch B-slot1 h0 (kt3)
    READ_A(1, 4);
    if (pf) STAGE(Bb, 32768, 0, 1, kt3);
    BARRIER(); LGKM0();
    MF16(4, 2, bf1);
    BARRIER();
    // ph8: (m4-7, n0-1, reuse) ; prefetch B-slot1 h1 ; counted vmcnt
    if (pf) STAGE(Bb, 32768, 1, 1, kt3);
    BARRIER();
    MF16(4, 0, bf0);
    if (pf) { VMCNT(4); } else { VMCNT(0); }
    BARRIER();
  }

  const long long crow0 = (long long)bi * 256 + wm * 128 + hi * 4;
  const int ccol = bj * 256 + wn * 64 + frow;
#pragma unroll
  for (int m = 0; m < 8; ++m)
#pragma unroll
    for (int j = 0; j < 4; ++j) {
      unsigned short* cp = C + (crow0 + m * 16 + j) * (long long)ldc + ccol;
#pragma unroll
      for (int n = 0; n < 4; ++n) cp[n * 16] = f2b(acc[m][j < 0 ? 0 : n][j]);
    }
}

// ============ single-buffer BK=64 core (gt / scores / pv) ============
// Tile: 128 x (NF*32), 4 waves (2x2). LDS chunk c of row r = global chunk c^(r&7).
template <int NF>
static __device__ __forceinline__ void gemm_loop(
    const unsigned short* __restrict__ A, const unsigned short* __restrict__ Bt,
    int lda, int ldb, int nk, int bi, int bj,
    unsigned short* lA, unsigned short* lB, floatx4 acc[4][NF]) {
  const int t = threadIdx.x, wave = t >> 6, lane = t & 63;
  const int wr = wave >> 1, wc = wave & 1;
  const int sr = lane >> 3;
  const int sc = ((lane & 7) ^ sr) * 8;
  const unsigned short* gA = A + (long long)(bi * 128 + wave * 32 + sr) * lda + sc;
  const unsigned short* gB = Bt + (long long)(bj * (NF * 32) + wave * (NF * 8) + sr) * ldb + sc;
  unsigned short* lAw = lA + wave * 2048;
  unsigned short* lBw = lB + wave * (NF * 512);
  const int frow = lane & 15, hi = lane >> 4;

  for (int ks = 0; ks < nk; ++ks) {
    const long long k0 = (long long)ks * 64;
    __syncthreads();
#pragma unroll
    for (int g = 0; g < 4; ++g)
      gload16(gA + (long long)g * 8 * lda + k0, lAw + g * 512);
#pragma unroll
    for (int g = 0; g < NF; ++g)
      gload16(gB + (long long)g * 8 * ldb + k0, lBw + g * 512);
    __syncthreads();
#pragma unroll
    for (int kk = 0; kk < 2; ++kk) {
      const int ch = (kk * 4 + hi) ^ (frow & 7);
      short8 af[4], bf[NF];
#pragma unroll
      for (int m = 0; m < 4; ++m)
        af[m] = *(const short8*)&lA[(wr * 64 + m * 16 + frow) * 64 + ch * 8];
#pragma unroll
      for (int n = 0; n < NF; ++n)
        bf[n] = *(const short8*)&lB[(wc * (NF * 16) + n * 16 + frow) * 64 + ch * 8];
#pragma unroll
      for (int m = 0; m < 4; ++m)
#pragma unroll
        for (int n = 0; n < NF; ++n)
          acc[m][n] = __builtin_amdgcn_mfma_f32_16x16x32_bf16(af[m], bf[n], acc[m][n], 0, 0, 0);
    }
  }
}

// Gt[j][i] = sum_d Wk[j][d]*Wq[i][d]  (both untransposed bf16), grid (8,8)
__global__ __launch_bounds__(256) void gt_kernel(
    const unsigned short* __restrict__ WkB, const unsigned short* __restrict__ WqB,
    unsigned short* __restrict__ Gt) {
  __shared__ __align__(16) unsigned short lA[8192], lB[8192];
  floatx4 acc[4][4] = {};
  gemm_loop<4>(WkB, WqB, 1024, 1024, 16, blockIdx.x, blockIdx.y, lA, lB, acc);
  const int tid = threadIdx.x, wave = tid >> 6, lane = tid & 63;
  const int wr = wave >> 1, wc = wave & 1, frow = lane & 15, hi = lane >> 4;
  const long long crow0 = (long long)blockIdx.x * 128 + wr * 64 + hi * 4;
  const int ccol = blockIdx.y * 128 + wc * 64 + frow;
#pragma unroll
  for (int m = 0; m < 4; ++m)
#pragma unroll
    for (int j = 0; j < 4; ++j) {
      unsigned short* cp = Gt + (crow0 + m * 16 + j) * 1024 + ccol;
#pragma unroll
      for (int n = 0; n < 4; ++n) cp[n * 16] = f2b(acc[m][n][j]);
    }
}

// 1-D grid 1088 (=8*136, XCD-swizzled). 128x64 tiles; S = T·Xk^T ;
// P = exp(S/32) bf16 (causal) ; row-sum partials -> Rpart[b][bj64][2048].
__global__ __launch_bounds__(256) void scores_exp(
    const unsigned short* __restrict__ Tb, const unsigned short* __restrict__ Xk,
    unsigned short* __restrict__ P, float* __restrict__ Rpart) {
  __shared__ __align__(16) unsigned short lA[8192], lB[4096];
  const int orig = blockIdx.x;
  const int w = (orig & 7) * 136 + (orig >> 3);
  const int b = w / 272;
  int t2 = w - b * 272;
  int bi = 0;
  while (t2 >= 2 * bi + 2) { t2 -= 2 * bi + 2; ++bi; }
  const int bj = t2;

  floatx4 acc[4][2] = {};
  gemm_loop<2>(Tb + (long long)b * 2048 * 1024, Xk + (long long)b * 2048 * 1024,
               1024, 1024, 16, bi, bj, lA, lB, acc);

  const int tid = threadIdx.x, wave = tid >> 6, lane = tid & 63;
  const int wr = wave >> 1, wc = wave & 1, frow = lane & 15, hi = lane >> 4;
  const bool diag = (bj >= 2 * bi);
  float rp[4][4];
#pragma unroll
  for (int m = 0; m < 4; ++m)
#pragma unroll
    for (int j = 0; j < 4; ++j) {
      const int rloc = wr * 64 + hi * 4 + m * 16 + j;
      const int rglob = bi * 128 + rloc;
      float s = 0.f;
#pragma unroll
      for (int n = 0; n < 2; ++n) {
        const int cglob = bj * 64 + wc * 32 + n * 16 + frow;
        float e = __expf(acc[m][n][j] * 0.03125f);
        if (diag && cglob > rglob) e = 0.f;
        acc[m][n][j] = e;
        s += e;
      }
      rp[m][j] = s;
    }
#pragma unroll
  for (int m = 0; m < 4; ++m)
#pragma unroll
    for (int j = 0; j < 4; ++j) {
      rp[m][j] += __shfl_xor(rp[m][j], 1);
      rp[m][j] += __shfl_xor(rp[m][j], 2);
      rp[m][j] += __shfl_xor(rp[m][j], 4);
      rp[m][j] += __shfl_xor(rp[m][j], 8);
    }
  unsigned short* C = P + (long long)b * 2048 * 2048;
  const long long crow0 = (long long)bi * 128 + wr * 64 + hi * 4;
  const int ccol = bj * 64 + wc * 32 + frow;
#pragma unroll
  for (int m = 0; m < 4; ++m)
#pragma unroll
    for (int j = 0; j < 4; ++j) {
      unsigned short* cp = C + (crow0 + m * 16 + j) * 2048LL + ccol;
      cp[0] = f2b(acc[m][0][j]);
      cp[16] = f2b(acc[m][1][j]);
    }
  __syncthreads();
  float* red = (float*)lA;
  if (frow == 0) {
#pragma unroll
    for (int m = 0; m < 4; ++m)
#pragma unroll
      for (int j = 0; j < 4; ++j)
        red[(wr * 64 + hi * 4 + m * 16 + j) * 2 + wc] = rp[m][j];
  }
  __syncthreads();
  if (tid < 128)
    Rpart[((long long)b * 32 + bj) * 2048 + bi * 128 + tid] = red[tid * 2] + red[tid * 2 + 1];
}

// Rinv[b][row] = 1 / sum_{bj64 <= row>>6} Rpart[b][bj64][row]
__global__ __launch_bounds__(256) void rowsum(
    const float* __restrict__ Rpart, float* __restrict__ Rinv) {
  const int t = blockIdx.x * 256 + threadIdx.x;  // 0..8191
  const int b = t >> 11, row = t & 2047;
  const int nb = (row >> 6) + 1;
  float s = 0.f;
  for (int bj = 0; bj < nb; ++bj) s += Rpart[(b * 32 + bj) * 2048 + row];
  Rinv[t] = 1.f / s;
}

// O = (P V) * Rinv ; 1-D grid 1024 (=8*128, XCD-swizzled), 128x64 tiles,
// heavy+light pairing: consecutive w pairs get bi = {p, 15-p}.
__global__ __launch_bounds__(256) void pv_kernel(
    const unsigned short* __restrict__ P, const unsigned short* __restrict__ Vt,
    const float* __restrict__ Rinv, float* __restrict__ out) {
  __shared__ __align__(16) unsigned short lA[8192], lB[4096];
  const int orig = blockIdx.x;
  const int w = (orig & 7) * 128 + (orig >> 3);
  const int tt = w >> 1, s = w & 1;
  const int p = tt & 7;
  const int bi = s ? 15 - p : p;
  const int b = (tt >> 3) & 3;
  const int bj = tt >> 5;  // 0..15
  floatx4 acc[4][2] = {};
  gemm_loop<2>(P + (long long)b * 2048 * 2048, Vt + (long long)b * 2048, 2048, 8192,
               (bi + 1) * 2, bi, bj, lA, lB, acc);
  const int tid = threadIdx.x, wave = tid >> 6, lane = tid & 63;
  const int wr = wave >> 1, wc = wave & 1, frow = lane & 15, hi = lane >> 4;
  float* C = out + (long long)b * 2048 * 1024;
  const float* Ri = Rinv + b * 2048;
#pragma unroll
  for (int m = 0; m < 4; ++m)
#pragma unroll
    for (int j = 0; j < 4; ++j) {
      const int row = bi * 128 + wr * 64 + hi * 4 + m * 16 + j;
      const float riv = Ri[row];
      float* cp = C + (long long)row * 1024 + bj * 64 + wc * 32 + frow;
      cp[0] = acc[m][0][j] * riv;
      cp[16] = acc[m][1][j] * riv;
    }
}

// All fp32->bf16 converts in ONE dispatch (3584 blocks).
__global__ __launch_bounds__(256) void cvtAll(
    const float* __restrict__ Xk, const float* __restrict__ Xv,
    const float* __restrict__ Xq, const float* __restrict__ Wq,
    const float* __restrict__ Wk, const float* __restrict__ Wv,
    unsigned short* __restrict__ Xb, unsigned short* __restrict__ WqB,
    unsigned short* __restrict__ WkB, unsigned short* __restrict__ WvT) {
  __shared__ unsigned short tile[64][65];
  const int bx = blockIdx.x, t = threadIdx.x;
  if (bx < 3072) {
    const int y = bx >> 10, sub = bx & 1023;
    const float* in = y == 0 ? Xv : (y == 1 ? Xq : Xk);
    unsigned short* o = Xb + (long long)y * XE;
    const int n4 = (int)(XE / 4), stride = 1024 * 256;
    for (int i = sub * 256 + t; i < n4; i += stride) {
      float4 x = ((const float4*)in)[i];
      ushort4 v;
      v.x = f2b(x.x); v.y = f2b(x.y); v.z = f2b(x.z); v.w = f2b(x.w);
      ((ushort4*)o)[i] = v;
    }
  } else if (bx < 3328) {
    const int w2 = bx - 3072;
    const int y = w2 >> 7, sub = w2 & 127;
    const float* in = y == 0 ? Wq : Wk;
    unsigned short* o = y == 0 ? WqB : WkB;
    const int n4 = (int)(WE / 4), stride = 128 * 256;
    for (int i = sub * 256 + t; i < n4; i += stride) {
      float4 x = ((const float4*)in)[i];
      ushort4 v;
      v.x = f2b(x.x); v.y = f2b(x.y); v.z = f2b(x.z); v.w = f2b(x.w);
      ((ushort4*)o)[i] = v;
    }
  } else {
    const int v = bx - 3328;
    const int i0 = (v & 15) * 64, j0 = (v >> 4) * 64;
#pragma unroll
    for (int r = 0; r < 16; ++r) {
      int lin = r * 256 + t;
      int i = lin >> 6, j = lin & 63;
      tile[i][j] = f2b(Wv[(long long)(i0 + i) * 1024 + j0 + j]);
    }
    __syncthreads();
#pragma unroll
    for (int r = 0; r < 16; ++r) {
      int lin = r * 256 + t;
      int o = lin >> 6, i = lin & 63;
      WvT[(long long)(j0 + o) * 1024 + i0 + i] = tile[i][o];
    }
  }
}

extern "C" void kernel_launch(void* const* d_in, const int* in_sizes, int n_in,
                              void* d_out, int out_size, void* d_ws, size_t ws_size,
                              hipStream_t stream) {
  const float* Xk = (const float*)d_in[0];
  const float* Xv = (const float*)d_in[1];
  const float* Xq = (const float*)d_in[2];
  const float* Wk = (const float*)d_in[3];
  const float* Wv = (const float*)d_in[4];
  const float* Wq = (const float*)d_in[5];
  float* out = (float*)d_out;

  // ws (ushort elems): Xb[3XE: Xv|Xq|Xk] WqB[WE] WkB[WE] WvT[WE] Gt[WE]
  //                    Tb[XE] Vt[XE] Rpart[4*32*2048 f32] Rinv[8192 f32]
  // Pbuf (bf16 P, 2XE) aliases Xv|Xq ONLY (both dead after projTV8).
  unsigned short* ws = (unsigned short*)d_ws;
  unsigned short* Xb = ws;
  unsigned short* WqB = ws + 3 * XE;
  unsigned short* WkB = WqB + WE;
  unsigned short* WvT = WkB + WE;
  unsigned short* Gt = WvT + WE;
  unsigned short* Tb = Gt + WE;
  unsigned short* Vt = Tb + XE;
  float* Rpart = (float*)(Vt + XE);
  float* Rinv = Rpart + 4 * 32 * 2048;
  unsigned short* Pbuf = ws;  // alias over Xv|Xq

  cvtAll<<<3584, 256, 0, stream>>>(Xk, Xv, Xq, Wq, Wk, Wv, Xb, WqB, WkB, WvT);
  gt_kernel<<<dim3(8, 8), 256, 0, stream>>>(WkB, WqB, Gt);
  projTV8<<<256, 512, 131072, stream>>>(Xb, WvT, Gt, Tb, Vt);
  scores_exp<<<1088, 256, 0, stream>>>(Tb, Xb + 2 * XE, Pbuf, Rpart);
  rowsum<<<32, 256, 0, stream>>>(Rpart, Rinv);
  pv_kernel<<<1024, 256, 0, stream>>>(Pbuf, Vt, Rinv, out);
}

// Round 9
// 157.891 us; speedup vs baseline: 1.2296x; 1.0759x over previous
//
#include <hip/hip_runtime.h>

// AttentionHead: B=4, S=2048, D=1024, fp32 in/out, bf16 MFMA compute.
// G = Wq·Wk^T  =>  S = Xq·G·Xk^T (K-projection eliminated).
// Max-free softmax: P = exp(S/32) fused into scores epilogue + row-sum partials;
// PV scales by 1/rowsum.
// projTV: 256x256 8-phase pipelined core (one machine round).
// scores/pv/gt: single-buffer BK=64 2-barrier core; pv uses per-XCD
// balanced LPT ordering with L2 P-panel grouping.

typedef __attribute__((ext_vector_type(8))) short short8;
typedef __attribute__((ext_vector_type(4))) float floatx4;

static constexpr long long XE = 8388608LL;  // 4*2048*1024
static constexpr long long WE = 1048576LL;  // 1024*1024

static __device__ __forceinline__ unsigned short f2b(float f) {
  unsigned u = __builtin_bit_cast(unsigned, f);
  u = (u + 0x7fffu + ((u >> 16) & 1u)) >> 16;
  return (unsigned short)u;
}

static __device__ __forceinline__ void gload16(const unsigned short* g, unsigned short* l) {
  __builtin_amdgcn_global_load_lds(
      (const __attribute__((address_space(1))) unsigned int*)g,
      (__attribute__((address_space(3))) unsigned int*)l, 16, 0, 0);
}

#define VMCNT(n) asm volatile("s_waitcnt vmcnt(" #n ")" ::: "memory")
#define LGKM0() asm volatile("s_waitcnt lgkmcnt(0)" ::: "memory")
#define BARRIER() do { asm volatile("" ::: "memory"); __builtin_amdgcn_s_barrier(); asm volatile("" ::: "memory"); } while (0)

// ============ projTV: 256x256, BK=64x2, 8-wave, 8-phase ============
#define STAGE(base, matoff, h, slot, kt) do {                                  \
    const unsigned short* _s = (base) + (h) * 131072 + (kt) * 64;              \
    char* _d = sb + (slot) * 65536 + (matoff) + (h) * 16384 + dwave;           \
    gload16(_s, (unsigned short*)_d);                                          \
    gload16(_s + 65536, (unsigned short*)(_d + 8192));                         \
  } while (0)

#define READ_A(slot, mb) do {                                                  \
    const char* _p = sb + (slot) * 65536 + aoffb + (mb) * 2048;                \
    af[0][0] = *(const short8*)(_p + c0);        af[0][1] = *(const short8*)(_p + c1); \
    af[1][0] = *(const short8*)(_p + 2048 + c0); af[1][1] = *(const short8*)(_p + 2048 + c1); \
    af[2][0] = *(const short8*)(_p + 4096 + c0); af[2][1] = *(const short8*)(_p + 4096 + c1); \
    af[3][0] = *(const short8*)(_p + 6144 + c0); af[3][1] = *(const short8*)(_p + 6144 + c1); \
  } while (0)

#define READ_B(slot, nb, bfx) do {                                             \
    const char* _p = sb + (slot) * 65536 + boffb + (nb) * 2048;                \
    bfx[0][0] = *(const short8*)(_p + c0);        bfx[0][1] = *(const short8*)(_p + c1); \
    bfx[1][0] = *(const short8*)(_p + 2048 + c0); bfx[1][1] = *(const short8*)(_p + 2048 + c1); \
  } while (0)

#define MF16(MB, NB, bfx) do {                                                 \
    __builtin_amdgcn_s_setprio(1);                                             \
    _Pragma("unroll")                                                          \
    for (int _m = 0; _m < 4; ++_m) {                                           \
      _Pragma("unroll")                                                        \
      for (int _n = 0; _n < 2; ++_n) {                                         \
        acc[(MB) + _m][(NB) + _n] = __builtin_amdgcn_mfma_f32_16x16x32_bf16(   \
            af[_m][0], bfx[_n][0], acc[(MB) + _m][(NB) + _n], 0, 0, 0);        \
        acc[(MB) + _m][(NB) + _n] = __builtin_amdgcn_mfma_f32_16x16x32_bf16(   \
            af[_m][1], bfx[_n][1], acc[(MB) + _m][(NB) + _n], 0, 0, 0);        \
      } }                                                                      \
    __builtin_amdgcn_s_setprio(0);                                             \
  } while (0)

__global__ __launch_bounds__(512, 2) void projTV8(
    const unsigned short* __restrict__ Xb, const unsigned short* __restrict__ WvT,
    const unsigned short* __restrict__ Gt, unsigned short* __restrict__ Tb,
    unsigned short* __restrict__ Vt) {
  extern __shared__ char sb[];
  const int orig = blockIdx.x;
  const int w = (orig & 7) * 32 + (orig >> 3);  // 256 = 8*32
  const unsigned short *Aop, *Bop;
  unsigned short* C;
  int ldc, bi, bj;
  if (w < 128) { Aop = Xb + XE; Bop = Gt; C = Tb; ldc = 1024; bi = w >> 2; bj = w & 3; }
  else { const int j = w - 128; Aop = WvT; Bop = Xb; C = Vt; ldc = 8192; bi = j & 3; bj = j >> 2; }

  const int tid = threadIdx.x, wave = tid >> 6, lane = tid & 63;
  const int wm = wave >> 2, wn = wave & 3, frow = lane & 15, hi = lane >> 4;
  const int r0 = tid >> 3, p0 = ((tid & 7) ^ (r0 & 7)) * 8;
  const int dwave = wave * 1024;
  const int sx = frow & 7;
  const int c0 = (hi ^ sx) * 16, c1 = ((4 + hi) ^ sx) * 16;
  const int aoffb = (wm * 128 + frow) * 128;
  const int boffb = 32768 + (wn * 64 + frow) * 128;
  const unsigned short* Ab = Aop + (long long)(bi * 256 + r0) * 1024 + p0;
  const unsigned short* Bb = Bop + (long long)(bj * 256 + r0) * 1024 + p0;

  short8 af[4][2], bf0[2][2], bf1[2][2];
  floatx4 acc[8][4] = {};

  STAGE(Ab, 0, 0, 0, 0);     STAGE(Ab, 0, 1, 0, 0);
  STAGE(Bb, 32768, 0, 0, 0); STAGE(Bb, 32768, 1, 0, 0);
  STAGE(Bb, 32768, 0, 1, 1); STAGE(Bb, 32768, 1, 1, 1);
  VMCNT(4);
  BARRIER();

  for (int t = 0; t < 8; ++t) {
    const int kt1 = 2 * t + 1, kt2 = 2 * t + 2, kt3 = 2 * t + 3;
    const bool pf = t < 7;
    READ_A(0, 0); READ_B(0, 0, bf0);
    STAGE(Ab, 0, 0, 1, kt1);
    BARRIER(); LGKM0();
    MF16(0, 0, bf0);
    BARRIER();
    READ_B(0, 2, bf1);
    STAGE(Ab, 0, 1, 1, kt1);
    BARRIER(); LGKM0();
    MF16(0, 2, bf1);
    BARRIER();
    READ_A(0, 4);
    if (pf) STAGE(Bb, 32768, 0, 0, kt2);
    BARRIER(); LGKM0();
    MF16(4, 2, bf1);
    BARRIER();
    if (pf) STAGE(Bb, 32768, 1, 0, kt2);
    BARRIER();
    MF16(4, 0, bf0);
    if (pf) { VMCNT(4); } else { VMCNT(0); }
    BARRIER();
    READ_A(1, 0); READ_B(1, 0, bf0);
    if (pf) STAGE(Ab, 0, 0, 0, kt2);
    BARRIER(); LGKM0();
    MF16(0, 0, bf0);
    BARRIER();
    READ_B(1, 2, bf1);
    if (pf) STAGE(Ab, 0, 1, 0, kt2);
    BARRIER(); LGKM0();
    MF16(0, 2, bf1);
    BARRIER();
    READ_A(1, 4);
    if (pf) STAGE(Bb, 32768, 0, 1, kt3);
    BARRIER(); LGKM0();
    MF16(4, 2, bf1);
    BARRIER();
    if (pf) STAGE(Bb, 32768, 1, 1, kt3);
    BARRIER();
    MF16(4, 0, bf0);
    if (pf) { VMCNT(4); } else { VMCNT(0); }
    BARRIER();
  }

  const long long crow0 = (long long)bi * 256 + wm * 128 + hi * 4;
  const int ccol = bj * 256 + wn * 64 + frow;
#pragma unroll
  for (int m = 0; m < 8; ++m)
#pragma unroll
    for (int j = 0; j < 4; ++j) {
      unsigned short* cp = C + (crow0 + m * 16 + j) * (long long)ldc + ccol;
#pragma unroll
      for (int n = 0; n < 4; ++n) cp[n * 16] = f2b(acc[m][n][j]);
    }
}

// ============ single-buffer BK=64 core (gt / scores / pv) ============
template <int NF>
static __device__ __forceinline__ void gemm_loop(
    const unsigned short* __restrict__ A, const unsigned short* __restrict__ Bt,
    int lda, int ldb, int nk, int bi, int bj,
    unsigned short* lA, unsigned short* lB, floatx4 acc[4][NF]) {
  const int t = threadIdx.x, wave = t >> 6, lane = t & 63;
  const int wr = wave >> 1, wc = wave & 1;
  const int sr = lane >> 3;
  const int sc = ((lane & 7) ^ sr) * 8;
  const unsigned short* gA = A + (long long)(bi * 128 + wave * 32 + sr) * lda + sc;
  const unsigned short* gB = Bt + (long long)(bj * (NF * 32) + wave * (NF * 8) + sr) * ldb + sc;
  unsigned short* lAw = lA + wave * 2048;
  unsigned short* lBw = lB + wave * (NF * 512);
  const int frow = lane & 15, hi = lane >> 4;

  for (int ks = 0; ks < nk; ++ks) {
    const long long k0 = (long long)ks * 64;
    __syncthreads();
#pragma unroll
    for (int g = 0; g < 4; ++g)
      gload16(gA + (long long)g * 8 * lda + k0, lAw + g * 512);
#pragma unroll
    for (int g = 0; g < NF; ++g)
      gload16(gB + (long long)g * 8 * ldb + k0, lBw + g * 512);
    __syncthreads();
#pragma unroll
    for (int kk = 0; kk < 2; ++kk) {
      const int ch = (kk * 4 + hi) ^ (frow & 7);
      short8 af[4], bf[NF];
#pragma unroll
      for (int m = 0; m < 4; ++m)
        af[m] = *(const short8*)&lA[(wr * 64 + m * 16 + frow) * 64 + ch * 8];
#pragma unroll
      for (int n = 0; n < NF; ++n)
        bf[n] = *(const short8*)&lB[(wc * (NF * 16) + n * 16 + frow) * 64 + ch * 8];
#pragma unroll
      for (int m = 0; m < 4; ++m)
#pragma unroll
        for (int n = 0; n < NF; ++n)
          acc[m][n] = __builtin_amdgcn_mfma_f32_16x16x32_bf16(af[m], bf[n], acc[m][n], 0, 0, 0);
    }
  }
}

// Gt[j][i] = sum_d Wk[j][d]*Wq[i][d], grid (8,8)
__global__ __launch_bounds__(256) void gt_kernel(
    const unsigned short* __restrict__ WkB, const unsigned short* __restrict__ WqB,
    unsigned short* __restrict__ Gt) {
  __shared__ __align__(16) unsigned short lA[8192], lB[8192];
  floatx4 acc[4][4] = {};
  gemm_loop<4>(WkB, WqB, 1024, 1024, 16, blockIdx.x, blockIdx.y, lA, lB, acc);
  const int tid = threadIdx.x, wave = tid >> 6, lane = tid & 63;
  const int wr = wave >> 1, wc = wave & 1, frow = lane & 15, hi = lane >> 4;
  const long long crow0 = (long long)blockIdx.x * 128 + wr * 64 + hi * 4;
  const int ccol = blockIdx.y * 128 + wc * 64 + frow;
#pragma unroll
  for (int m = 0; m < 4; ++m)
#pragma unroll
    for (int j = 0; j < 4; ++j) {
      unsigned short* cp = Gt + (crow0 + m * 16 + j) * 1024 + ccol;
#pragma unroll
      for (int n = 0; n < 4; ++n) cp[n * 16] = f2b(acc[m][n][j]);
    }
}

// 1-D grid 1088 (=8*136, XCD-swizzled). 128x64 tiles; S = T·Xk^T ;
// P = exp(S/32) bf16 (causal) ; row-sum partials -> Rpart[b][bj64][2048].
__global__ __launch_bounds__(256) void scores_exp(
    const unsigned short* __restrict__ Tb, const unsigned short* __restrict__ Xk,
    unsigned short* __restrict__ P, float* __restrict__ Rpart) {
  __shared__ __align__(16) unsigned short lA[8192], lB[4096];
  const int orig = blockIdx.x;
  const int w = (orig & 7) * 136 + (orig >> 3);
  const int b = w / 272;
  int t2 = w - b * 272;
  int bi = 0;
  while (t2 >= 2 * bi + 2) { t2 -= 2 * bi + 2; ++bi; }
  const int bj = t2;

  floatx4 acc[4][2] = {};
  gemm_loop<2>(Tb + (long long)b * 2048 * 1024, Xk + (long long)b * 2048 * 1024,
               1024, 1024, 16, bi, bj, lA, lB, acc);

  const int tid = threadIdx.x, wave = tid >> 6, lane = tid & 63;
  const int wr = wave >> 1, wc = wave & 1, frow = lane & 15, hi = lane >> 4;
  const bool diag = (bj >= 2 * bi);
  float rp[4][4];
#pragma unroll
  for (int m = 0; m < 4; ++m)
#pragma unroll
    for (int j = 0; j < 4; ++j) {
      const int rloc = wr * 64 + hi * 4 + m * 16 + j;
      const int rglob = bi * 128 + rloc;
      float s = 0.f;
#pragma unroll
      for (int n = 0; n < 2; ++n) {
        const int cglob = bj * 64 + wc * 32 + n * 16 + frow;
        float e = __expf(acc[m][n][j] * 0.03125f);
        if (diag && cglob > rglob) e = 0.f;
        acc[m][n][j] = e;
        s += e;
      }
      rp[m][j] = s;
    }
#pragma unroll
  for (int m = 0; m < 4; ++m)
#pragma unroll
    for (int j = 0; j < 4; ++j) {
      rp[m][j] += __shfl_xor(rp[m][j], 1);
      rp[m][j] += __shfl_xor(rp[m][j], 2);
      rp[m][j] += __shfl_xor(rp[m][j], 4);
      rp[m][j] += __shfl_xor(rp[m][j], 8);
    }
  unsigned short* C = P + (long long)b * 2048 * 2048;
  const long long crow0 = (long long)bi * 128 + wr * 64 + hi * 4;
  const int ccol = bj * 64 + wc * 32 + frow;
#pragma unroll
  for (int m = 0; m < 4; ++m)
#pragma unroll
    for (int j = 0; j < 4; ++j) {
      unsigned short* cp = C + (crow0 + m * 16 + j) * 2048LL + ccol;
      cp[0] = f2b(acc[m][0][j]);
      cp[16] = f2b(acc[m][1][j]);
    }
  __syncthreads();
  float* red = (float*)lA;
  if (frow == 0) {
#pragma unroll
    for (int m = 0; m < 4; ++m)
#pragma unroll
      for (int j = 0; j < 4; ++j)
        red[(wr * 64 + hi * 4 + m * 16 + j) * 2 + wc] = rp[m][j];
  }
  __syncthreads();
  if (tid < 128)
    Rpart[((long long)b * 32 + bj) * 2048 + bi * 128 + tid] = red[tid * 2] + red[tid * 2 + 1];
}

// Rinv[b][row] = 1 / sum_{bj64 <= row>>6} Rpart[b][bj64][row]
__global__ __launch_bounds__(256) void rowsum(
    const float* __restrict__ Rpart, float* __restrict__ Rinv) {
  const int t = blockIdx.x * 256 + threadIdx.x;  // 0..8191
  const int b = t >> 11, row = t & 2047;
  const int nb = (row >> 6) + 1;
  float s = 0.f;
  for (int bj = 0; bj < nb; ++bj) s += Rpart[(b * 32 + bj) * 2048 + row];
  Rinv[t] = 1.f / s;
}

// O = (P V) * Rinv ; grid 1024. Per-XCD balanced LPT: XCD c = orig&7 gets
// 8 blocks of EVERY bi (equal total K per XCD), heavy-first (bi=15 down);
// per (c,bi) the 8 blocks share one (b, P-panel) -> L2 reuse.
__global__ __launch_bounds__(256) void pv_kernel(
    const unsigned short* __restrict__ P, const unsigned short* __restrict__ Vt,
    const float* __restrict__ Rinv, float* __restrict__ out) {
  __shared__ __align__(16) unsigned short lA[8192], lB[4096];
  const int orig = blockIdx.x;
  const int c = orig & 7, i = orig >> 3;  // XCD, order within XCD (0..127)
  const int bi = 15 - (i >> 3);           // heavy-first
  const int rr = (i & 7) + c * 8;         // 0..63
  const int b = rr >> 4, bj = rr & 15;
  floatx4 acc[4][2] = {};
  gemm_loop<2>(P + (long long)b * 2048 * 2048, Vt + (long long)b * 2048, 2048, 8192,
               (bi + 1) * 2, bi, bj, lA, lB, acc);
  const int tid = threadIdx.x, wave = tid >> 6, lane = tid & 63;
  const int wr = wave >> 1, wc = wave & 1, frow = lane & 15, hi = lane >> 4;
  float* C = out + (long long)b * 2048 * 1024;
  const float* Ri = Rinv + b * 2048;
#pragma unroll
  for (int m = 0; m < 4; ++m)
#pragma unroll
    for (int j = 0; j < 4; ++j) {
      const int row = bi * 128 + wr * 64 + hi * 4 + m * 16 + j;
      const float riv = Ri[row];
      float* cp = C + (long long)row * 1024 + bj * 64 + wc * 32 + frow;
      cp[0] = acc[m][0][j] * riv;
      cp[16] = acc[m][1][j] * riv;
    }
}

// All fp32->bf16 converts, 16B stores (8 elems/thread/iter). Grid 2048:
// [0,1536): X tensors ; [1536,1792): Wq,Wk ; [1792,2048): Wv transpose.
__global__ __launch_bounds__(256) void cvtAll(
    const float* __restrict__ Xk, const float* __restrict__ Xv,
    const float* __restrict__ Xq, const float* __restrict__ Wq,
    const float* __restrict__ Wk, const float* __restrict__ Wv,
    unsigned short* __restrict__ Xb, unsigned short* __restrict__ WqB,
    unsigned short* __restrict__ WkB, unsigned short* __restrict__ WvT) {
  __shared__ unsigned short tile[64][65];
  const int bx = blockIdx.x, t = threadIdx.x;
  if (bx < 1536) {
    const int y = bx / 512, sub = bx - y * 512;
    const float* in = y == 0 ? Xv : (y == 1 ? Xq : Xk);
    unsigned short* o = Xb + (long long)y * XE;
    const int n8 = (int)(XE / 8), stride = 512 * 256;
    for (int i = sub * 256 + t; i < n8; i += stride) {
      float4 a = ((const float4*)in)[2 * i];
      float4 d = ((const float4*)in)[2 * i + 1];
      short8 v;
      v[0] = (short)f2b(a.x); v[1] = (short)f2b(a.y);
      v[2] = (short)f2b(a.z); v[3] = (short)f2b(a.w);
      v[4] = (short)f2b(d.x); v[5] = (short)f2b(d.y);
      v[6] = (short)f2b(d.z); v[7] = (short)f2b(d.w);
      ((short8*)o)[i] = v;
    }
  } else if (bx < 1792) {
    const int w2 = bx - 1536;
    const int y = w2 >> 7, sub = w2 & 127;
    const float* in = y == 0 ? Wq : Wk;
    unsigned short* o = y == 0 ? WqB : WkB;
    const int n8 = (int)(WE / 8), stride = 128 * 256;
    for (int i = sub * 256 + t; i < n8; i += stride) {
      float4 a = ((const float4*)in)[2 * i];
      float4 d = ((const float4*)in)[2 * i + 1];
      short8 v;
      v[0] = (short)f2b(a.x); v[1] = (short)f2b(a.y);
      v[2] = (short)f2b(a.z); v[3] = (short)f2b(a.w);
      v[4] = (short)f2b(d.x); v[5] = (short)f2b(d.y);
      v[6] = (short)f2b(d.z); v[7] = (short)f2b(d.w);
      ((short8*)o)[i] = v;
    }
  } else {
    const int v = bx - 1792;
    const int i0 = (v & 15) * 64, j0 = (v >> 4) * 64;
#pragma unroll
    for (int r = 0; r < 16; ++r) {
      int lin = r * 256 + t;
      int i = lin >> 6, j = lin & 63;
      tile[i][j] = f2b(Wv[(long long)(i0 + i) * 1024 + j0 + j]);
    }
    __syncthreads();
#pragma unroll
    for (int r = 0; r < 16; ++r) {
      int lin = r * 256 + t;
      int o = lin >> 6, i = lin & 63;
      WvT[(long long)(j0 + o) * 1024 + i0 + i] = tile[i][o];
    }
  }
}

extern "C" void kernel_launch(void* const* d_in, const int* in_sizes, int n_in,
                              void* d_out, int out_size, void* d_ws, size_t ws_size,
                              hipStream_t stream) {
  const float* Xk = (const float*)d_in[0];
  const float* Xv = (const float*)d_in[1];
  const float* Xq = (const float*)d_in[2];
  const float* Wk = (const float*)d_in[3];
  const float* Wv = (const float*)d_in[4];
  const float* Wq = (const float*)d_in[5];
  float* out = (float*)d_out;

  // ws (ushort elems): Xb[3XE: Xv|Xq|Xk] WqB[WE] WkB[WE] WvT[WE] Gt[WE]
  //                    Tb[XE] Vt[XE] Rpart[4*32*2048 f32] Rinv[8192 f32]
  // Pbuf (bf16 P, 2XE) aliases Xv|Xq ONLY (both dead after projTV8).
  unsigned short* ws = (unsigned short*)d_ws;
  unsigned short* Xb = ws;
  unsigned short* WqB = ws + 3 * XE;
  unsigned short* WkB = WqB + WE;
  unsigned short* WvT = WkB + WE;
  unsigned short* Gt = WvT + WE;
  unsigned short* Tb = Gt + WE;
  unsigned short* Vt = Tb + XE;
  float* Rpart = (float*)(Vt + XE);
  float* Rinv = Rpart + 4 * 32 * 2048;
  unsigned short* Pbuf = ws;  // alias over Xv|Xq

  cvtAll<<<2048, 256, 0, stream>>>(Xk, Xv, Xq, Wq, Wk, Wv, Xb, WqB, WkB, WvT);
  gt_kernel<<<dim3(8, 8), 256, 0, stream>>>(WkB, WqB, Gt);
  projTV8<<<256, 512, 131072, stream>>>(Xb, WvT, Gt, Tb, Vt);
  scores_exp<<<1088, 256, 0, stream>>>(Tb, Xb + 2 * XE, Pbuf, Rpart);
  rowsum<<<32, 256, 0, stream>>>(Rpart, Rinv);
  pv_kernel<<<1024, 256, 0, stream>>>(Pbuf, Vt, Rinv, out);
}